// Round 9
// baseline (472.145 us; speedup 1.0000x reference)
//
#include <hip/hip_runtime.h>
#include <hip/hip_bf16.h>

typedef __bf16 bf16;
typedef __bf16 bf16x2 __attribute__((ext_vector_type(2)));
typedef __bf16 bf16x4 __attribute__((ext_vector_type(4)));
typedef __bf16 bf16x8 __attribute__((ext_vector_type(8)));
typedef float  f32x4  __attribute__((ext_vector_type(4)));
typedef int    i32x2  __attribute__((ext_vector_type(2)));
typedef int    i32x4  __attribute__((ext_vector_type(4)));

#define NEG_INF (-1e9f)
#define N_SCENES 2048
#define PGRID    1024             // persistent: 2 scenes/block, 4 blocks/CU

#if defined(__has_builtin)
#if __has_builtin(__builtin_amdgcn_exp2f)
#define EXP2(x) __builtin_amdgcn_exp2f(x)
#endif
#endif
#ifndef EXP2
#define EXP2(x) exp2f(x)
#endif

// v_permlane32_swap_b32: a' = {a.lo32lanes, b.lo32lanes}, b' = {a.hi, b.hi}
static __device__ __forceinline__ void pl32(int& a, int& b) {
#if defined(__has_builtin) && __has_builtin(__builtin_amdgcn_permlane32_swap)
    i32x2 res = __builtin_amdgcn_permlane32_swap(a, b, false, false);
    a = res[0]; b = res[1];
#else
    asm("v_permlane32_swap_b32 %0, %1" : "+v"(a), "+v"(b));
#endif
}

// pack two f32 -> one dword of 2 bf16 (compiler emits v_cvt_pk_bf16_f32)
static __device__ __forceinline__ int pk2(float x, float y) {
    bf16x2 t = {(bf16)x, (bf16)y};
    return __builtin_bit_cast(int, t);
}

// Quad-transpose transform (no LDS, no bpermute):
// sources a0,a1 (tile A words), b0,b1 (tile B words), each word = 2 bf16.
// Source layout: lane(r,qd') word w of tile T = elems [T*16 + qd'*4 + 2w, +1].
// Target: word j at lane(r,qd) = elems [qd*8 + 2j, +1] (A for qd<2, B else).
static __device__ __forceinline__ i32x4 qtrans(int a0, int a1, int b0, int b1,
                                               bool qodd) {
    i32x4 out;
    pl32(a0, b0);                       // a0={A.lo,B.lo}  b0={A.hi,B.hi}
    int y2 = __shfl_xor(b0, 16);
    int x2 = __shfl_xor(a0, 16);
    out[0] = qodd ? y2 : a0;
    out[2] = qodd ? b0 : x2;
    pl32(a1, b1);
    int y2b = __shfl_xor(b1, 16);
    int x2b = __shfl_xor(a1, 16);
    out[1] = qodd ? y2b : a1;
    out[3] = qodd ? b1 : x2b;
    return out;
}

// ---------------------------------------------------------------------------
// Prep: block 0: exclusive prefix sum of agents (B=2048); blocks 1..64:
// fp32 -> bf16 weight conversion into workspace.
// ---------------------------------------------------------------------------
__global__ __launch_bounds__(256) void prep_kernel(
    const float* __restrict__ w_in, const float* __restrict__ w_out,
    const int* __restrict__ agents,
    bf16* __restrict__ w_in_b, bf16* __restrict__ w_out_b, int* __restrict__ offs)
{
    __shared__ int tot[256];
    const int t = threadIdx.x;
    if (blockIdx.x == 0) {
        int loc[8]; int s = 0;
        #pragma unroll
        for (int j = 0; j < 8; ++j) { loc[j] = agents[t * 8 + j]; s += loc[j]; }
        tot[t] = s;
        __syncthreads();
        for (int o = 1; o < 256; o <<= 1) {
            int v = (t >= o) ? tot[t - o] : 0;
            __syncthreads();
            tot[t] += v;
            __syncthreads();
        }
        int run = tot[t] - s;
        #pragma unroll
        for (int j = 0; j < 8; ++j) { offs[t * 8 + j] = run; run += loc[j]; }
    } else {
        int i = (blockIdx.x - 1) * 1024 + t * 4;
        float4 v; bf16* dst;
        if (i < 49152) { v = *(const float4*)(w_in + i);            dst = w_in_b + i; }
        else           { v = *(const float4*)(w_out + (i - 49152)); dst = w_out_b + (i - 49152); }
        bf16x4 o = { (bf16)v.x, (bf16)v.y, (bf16)v.z, (bf16)v.w };
        *(bf16x4*)dst = o;
    }
}

// ---------------------------------------------------------------------------
// R13: persistent grid over the VERBATIM R7 body (best measured: 76us attn,
// clean 64-VGPR build under (256,4): K,V via 32KB LDS, Q in regs, qtrans
// quad-transposes, ctxS overlays Kld). R12's spill mechanism identified:
// its loop placed zero-fill + 32-reg xa loads BEFORE the loop-top barrier,
// so the compiler pipelined them above the previous scene's stage-3 (+40
// regs liveness -> spill-to-budget, +430MB scratch). Fix: __syncthreads()
// is the FIRST statement of the loop body -- a full memory fence that
// forbids cross-iteration hoisting AND protects LDS reuse. PGRID=1024:
// exactly 2 scenes/block (uniform), 4 blocks/CU <= LDS cap 5; dispatch
// count halves; body runs I$-warm for 50% of scene executions.
// Only other delta vs R7: (1/sqrt32)*log2e folded into the Q pack (passed
// R11/R12), deleting the per-mt S-scale VALU pass.
// MFMA 16x16x32_bf16: A[m=lane&15][k=quad*8+jj], B[k=quad*8+jj][n=lane&15],
// C/D: col=lane&15, row=quad*4+reg.
// ---------------------------------------------------------------------------
__global__ __launch_bounds__(256, 4) void attn_kernel(
    const float* __restrict__ att_in,
    const float* __restrict__ b_in, const float* __restrict__ b_out,
    const bf16* __restrict__ w_in_b, const bf16* __restrict__ w_out_b,
    const int* __restrict__ agents, const int* __restrict__ offs,
    float* __restrict__ out)
{
    __shared__ bf16 s_lds[4 * 4096];   // 32 KB

    const int tid  = threadIdx.x;
    const int lane = tid & 63;
    const int w    = tid >> 6;         // wave id == head id
    const int h    = w;
    const int r    = lane & 15;
    const int qd   = lane >> 4;        // quad 0..3
    const int q1   = qd & 1;
    const int qh   = qd >> 1;
    const bool qodd = (q1 != 0);

    bf16* Kld = s_lds + h * 4096;      // K[64][32] swizzled; later ctxS[4mt][64][8]
    bf16* vT  = Kld + 2048;            // vT[32][64]

    const float SC = 0.25503484f;      // (1/sqrt(32)) * log2(e), folded into Q

    #pragma unroll 1
    for (int b = blockIdx.x; b < N_SCENES; b += PGRID) {

        // Fence FIRST: previous scene's stage-3 LDS reads complete, and the
        // compiler cannot hoist this scene's global loads above it.
        __syncthreads();

        const int nb  = agents[b];
        const int off = offs[b];
        const int mtc = (nb + 15) >> 4;    // live m-tiles (1..4)

        // ---- zero-fill output rows [nb, 64) ----
        {
            const float4 z4 = make_float4(0.f, 0.f, 0.f, 0.f);
            const int nz = (64 - nb) * 32;
            for (int i = tid; i < nz; i += 256) {
                int row = nb + (i >> 5);
                *(float4*)(out + ((size_t)b * 64 + row) * 128 + (i & 31) * 4) = z4;
            }
        }

        // ---- zero vT units for agents >= mtc*16 (keep PV inputs finite) ----
        {
            bf16x4 z4 = {(bf16)0.f,(bf16)0.f,(bf16)0.f,(bf16)0.f};
            int zrow = lane >> 1, zh = lane & 1;     // 32 rows x 2 halves
            #pragma unroll
            for (int un = 2; un < 8; ++un)
                if (un >= 2 * mtc) {
                    int uu = un ^ (zrow & 7);
                    *(bf16x4*)(vT + zrow * 64 + uu * 8 + zh * 4) = z4;
                }
        }

        // ---- x fragments from global (rows >= nb -> 0) ----
        bf16x8 xa[4][4];
        #pragma unroll
        for (int mt = 0; mt < 4; ++mt) {
            const int xrow = mt * 16 + r;
            const bool vr = xrow < nb;
            const float* px = att_in + (((size_t)(off + xrow)) << 7) + qd * 8;
            #pragma unroll
            for (int ks = 0; ks < 4; ++ks) {
                float4 lo = make_float4(0.f,0.f,0.f,0.f), hi = lo;
                if (vr) {
                    lo = *(const float4*)(px + ks * 32);
                    hi = *(const float4*)(px + ks * 32 + 4);
                }
                i32x4 pw4 = { pk2(lo.x, lo.y), pk2(lo.z, lo.w),
                              pk2(hi.x, hi.y), pk2(hi.z, hi.w) };
                xa[mt][ks] = __builtin_bit_cast(bf16x8, pw4);
            }
        }

        // ---- stage 1a: Q tiles -> registers (packed, bias+scale folded) ----
        // qreg[mt][jt] @ lane(r,qd) = SC*(Q[agent=mt*16+r][jt*16+qd*4+reg]+b)
        bf16x4 qreg[4][2];
        #pragma unroll
        for (int jt = 0; jt < 2; ++jt) {
            const int j0 = h * 32 + jt * 16;
            const bf16* pw = w_in_b + (size_t)(j0 + r) * 128 + qd * 8;
            bf16x8 wb[4];
            #pragma unroll
            for (int ks = 0; ks < 4; ++ks)
                wb[ks] = *(const bf16x8*)(pw + ks * 32);
            const float4 b4 = *(const float4*)(b_in + j0 + qd * 4);
            #pragma unroll
            for (int mt = 0; mt < 4; ++mt)
                if (mt < mtc) {
                    f32x4 acc = {0.f,0.f,0.f,0.f};
                    #pragma unroll
                    for (int ks = 0; ks < 4; ++ks)
                        acc = __builtin_amdgcn_mfma_f32_16x16x32_bf16(wb[ks], xa[mt][ks], acc, 0, 0, 0);
                    qreg[mt][jt] = (bf16x4){(bf16)((acc[0]+b4.x)*SC), (bf16)((acc[1]+b4.y)*SC),
                                            (bf16)((acc[2]+b4.z)*SC), (bf16)((acc[3]+b4.w)*SC)};
                }
        }

        // ---- stage 1b: K tiles -> LDS (swizzled) ----
        #pragma unroll
        for (int jt = 0; jt < 2; ++jt) {
            const int j0 = 128 + h * 32 + jt * 16;
            const bf16* pw = w_in_b + (size_t)(j0 + r) * 128 + qd * 8;
            bf16x8 wb[4];
            #pragma unroll
            for (int ks = 0; ks < 4; ++ks)
                wb[ks] = *(const bf16x8*)(pw + ks * 32);
            const float4 b4 = *(const float4*)(b_in + j0 + qd * 4);
            #pragma unroll
            for (int mt = 0; mt < 4; ++mt)
                if (mt < mtc) {
                    f32x4 acc = {0.f,0.f,0.f,0.f};
                    #pragma unroll
                    for (int ks = 0; ks < 4; ++ks)
                        acc = __builtin_amdgcn_mfma_f32_16x16x32_bf16(wb[ks], xa[mt][ks], acc, 0, 0, 0);
                    bf16x4 pk = {(bf16)(acc[0]+b4.x), (bf16)(acc[1]+b4.y),
                                 (bf16)(acc[2]+b4.z), (bf16)(acc[3]+b4.w)};
                    int rowa = mt * 16 + r;
                    int uu = (jt * 2 + qh) ^ (rowa & 3);
                    *(bf16x4*)(Kld + rowa * 32 + uu * 8 + q1 * 4) = pk;
                }
        }

        // ---- stage 1c: V tiles -> LDS transposed ----
        #pragma unroll
        for (int jt = 0; jt < 2; ++jt) {
            const int j0 = 256 + h * 32 + jt * 16;
            const bf16* pw = w_in_b + (size_t)(j0 + r) * 128 + qd * 8;
            bf16x8 wb[4];
            #pragma unroll
            for (int ks = 0; ks < 4; ++ks)
                wb[ks] = *(const bf16x8*)(pw + ks * 32);
            const float bv = b_in[j0 + r];
            #pragma unroll
            for (int mt = 0; mt < 4; ++mt)
                if (mt < mtc) {
                    f32x4 acc = {0.f,0.f,0.f,0.f};
                    #pragma unroll
                    for (int ks = 0; ks < 4; ++ks)
                        acc = __builtin_amdgcn_mfma_f32_16x16x32_bf16(xa[mt][ks], wb[ks], acc, 0, 0, 0);
                    bf16x4 pk = {(bf16)(acc[0]+bv), (bf16)(acc[1]+bv),
                                 (bf16)(acc[2]+bv), (bf16)(acc[3]+bv)};
                    int rowd = jt * 16 + r;
                    int uu = (mt * 2 + qh) ^ (rowd & 7);
                    *(bf16x4*)(vT + rowd * 64 + uu * 8 + q1 * 4) = pk;
                }
        }

        // ---- stage 2 preloads: K A-frags, V^T A-frags (wave-local LDS) ----
        bf16x8 kf[4];
        #pragma unroll
        for (int nt = 0; nt < 4; ++nt)
            if (nt < mtc) {
                int row = nt * 16 + r;
                kf[nt] = *(const bf16x8*)(Kld + row * 32 + (qd ^ (row & 3)) * 8);
            }
        bf16x8 vf[2][2];
        #pragma unroll
        for (int dt = 0; dt < 2; ++dt)
            #pragma unroll
            for (int hk = 0; hk < 2; ++hk) {
                int row = dt * 16 + r;
                vf[dt][hk] = *(const bf16x8*)(vT + row * 64 + ((hk * 4 + qd) ^ (row & 7)) * 8);
            }
        bf16x8 wof[2][4]; float4 bo4[2];
        #pragma unroll
        for (int t2 = 0; t2 < 2; ++t2) {
            const int jg = (h * 2 + t2) * 16;
            const bf16* pw = w_out_b + (size_t)(jg + r) * 128 + qd * 8;
            #pragma unroll
            for (int s = 0; s < 4; ++s)
                wof[t2][s] = *(const bf16x8*)(pw + s * 32);
            bo4[t2] = *(const float4*)(b_out + jg + qd * 4);
        }

        // ---- stage 2: per query-tile mt: S^T -> softmax -> P^T -> PV ----
        #pragma unroll
        for (int mt = 0; mt < 4; ++mt)
            if (mt < mtc) {
                // qf = B-frag Q[agent=r][d=qd*8+jj] via quad-transform
                i32x2 qa = __builtin_bit_cast(i32x2, qreg[mt][0]);
                i32x2 qb = __builtin_bit_cast(i32x2, qreg[mt][1]);
                i32x4 qw = qtrans(qa[0], qa[1], qb[0], qb[1], qodd);
                bf16x8 qf = __builtin_bit_cast(bf16x8, qw);

                f32x4 S[4];
                #pragma unroll
                for (int nt = 0; nt < 4; ++nt)
                    if (nt < mtc) {
                        f32x4 z = {0.f,0.f,0.f,0.f};
                        S[nt] = __builtin_amdgcn_mfma_f32_16x16x32_bf16(kf[nt], qf, z, 0, 0, 0);
                    }
                // masked softmax (log2 domain; scale pre-folded into Q)
                #pragma unroll
                for (int nt = 0; nt < 4; ++nt) {
                    if (nt < mtc) {
                        #pragma unroll
                        for (int i = 0; i < 4; ++i) {
                            bool kv = (nt * 16 + qd * 4 + i) < nb;
                            S[nt][i] = kv ? S[nt][i] : NEG_INF;
                        }
                    } else {
                        S[nt] = (f32x4){NEG_INF, NEG_INF, NEG_INF, NEG_INF};
                    }
                }
                float tm[4];
                #pragma unroll
                for (int nt = 0; nt < 4; ++nt)
                    tm[nt] = fmaxf(fmaxf(S[nt][0], S[nt][1]), fmaxf(S[nt][2], S[nt][3]));
                float mx = fmaxf(fmaxf(tm[0], tm[1]), fmaxf(tm[2], tm[3]));
                mx = fmaxf(mx, __shfl_xor(mx, 16));
                mx = fmaxf(mx, __shfl_xor(mx, 32));
                float lt[4];
                #pragma unroll
                for (int nt = 0; nt < 4; ++nt) {
                    float e0 = EXP2(S[nt][0] - mx), e1 = EXP2(S[nt][1] - mx);
                    float e2 = EXP2(S[nt][2] - mx), e3 = EXP2(S[nt][3] - mx);
                    S[nt][0] = e0; S[nt][1] = e1; S[nt][2] = e2; S[nt][3] = e3;
                    lt[nt] = (e0 + e1) + (e2 + e3);
                }
                float l = (lt[0] + lt[1]) + (lt[2] + lt[3]);
                l += __shfl_xor(l, 16);
                l += __shfl_xor(l, 32);
                const float rl = 1.0f / l;
                #pragma unroll
                for (int nt = 0; nt < 4; ++nt)
                    #pragma unroll
                    for (int i = 0; i < 4; ++i)
                        S[nt][i] *= rl;                   // invalid keys -> exact 0

                // PV: O^T = V^T * P^T ; P^T frags via quad-transform
                f32x4 o0 = {0.f,0.f,0.f,0.f}, o1 = {0.f,0.f,0.f,0.f};
                #pragma unroll
                for (int hk = 0; hk < 2; ++hk)
                    if (hk * 2 < mtc) {
                        int a0 = pk2(S[2*hk  ][0], S[2*hk  ][1]);
                        int a1 = pk2(S[2*hk  ][2], S[2*hk  ][3]);
                        int b0 = pk2(S[2*hk+1][0], S[2*hk+1][1]);
                        int b1 = pk2(S[2*hk+1][2], S[2*hk+1][3]);
                        i32x4 pw4 = qtrans(a0, a1, b0, b1, qodd);
                        bf16x8 pf = __builtin_bit_cast(bf16x8, pw4);
                        o0 = __builtin_amdgcn_mfma_f32_16x16x32_bf16(vf[0][hk], pf, o0, 0, 0, 0);
                        o1 = __builtin_amdgcn_mfma_f32_16x16x32_bf16(vf[1][hk], pf, o1, 0, 0, 0);
                    }

                // ctx^T B-frag via quad-transform -> one b128 LDS write (ctxS
                // overlays Kld; kf register-resident; wave-local region)
                {
                    int a0 = pk2(o0[0], o0[1]);
                    int a1 = pk2(o0[2], o0[3]);
                    int b0 = pk2(o1[0], o1[1]);
                    int b1 = pk2(o1[2], o1[3]);
                    i32x4 cw = qtrans(a0, a1, b0, b1, qodd);
                    bf16x8 cf = __builtin_bit_cast(bf16x8, cw);
                    *(bf16x8*)(Kld + mt * 512 + lane * 8) = cf;   // ctxS[h][mt][lane]
                }
            }
        __syncthreads();

        // ---- stage 3: out^T = W_out * ctx^T ; float4 stores ----
        #pragma unroll
        for (int mt = 0; mt < 4; ++mt)
            if (mt < mtc) {
                bf16x8 cb[4];
                #pragma unroll
                for (int s = 0; s < 4; ++s)
                    cb[s] = *(const bf16x8*)(s_lds + s * 4096 + mt * 512 + lane * 8);
                const int rowa = mt * 16 + r;
                #pragma unroll
                for (int t2 = 0; t2 < 2; ++t2) {
                    f32x4 acc = {0.f,0.f,0.f,0.f};
                    #pragma unroll
                    for (int s = 0; s < 4; ++s)
                        acc = __builtin_amdgcn_mfma_f32_16x16x32_bf16(wof[t2][s], cb[s], acc, 0, 0, 0);
                    if (rowa < nb) {
                        float4 o4 = make_float4(acc[0] + bo4[t2].x, acc[1] + bo4[t2].y,
                                                acc[2] + bo4[t2].z, acc[3] + bo4[t2].w);
                        *(float4*)(out + ((size_t)b * 64 + rowa) * 128
                                   + (w * 2 + t2) * 16 + qd * 4) = o4;
                    }
                }
            }
    }
}

extern "C" void kernel_launch(void* const* d_in, const int* in_sizes, int n_in,
                              void* d_out, int out_size, void* d_ws, size_t ws_size,
                              hipStream_t stream)
{
    const float* att_in = (const float*)d_in[0];
    const float* w_in   = (const float*)d_in[1];
    const float* b_in   = (const float*)d_in[2];
    const float* w_out  = (const float*)d_in[3];
    const float* b_out  = (const float*)d_in[4];
    const int*   agents = (const int*)d_in[5];

    bf16* w_in_b  = (bf16*)d_ws;                         // 49152 * 2B
    bf16* w_out_b = w_in_b + 49152;                      // 16384 * 2B
    int*  offs    = (int*)((char*)d_ws + 98304 + 32768); // 2048 * 4B

    prep_kernel<<<65, 256, 0, stream>>>(w_in, w_out, agents, w_in_b, w_out_b, offs);
    attn_kernel<<<PGRID, 256, 0, stream>>>(att_in, b_in, b_out, w_in_b, w_out_b,
                                           agents, offs, (float*)d_out);
}

// Round 10
// 194.475 us; speedup vs baseline: 2.4278x; 2.4278x over previous
//
#include <hip/hip_runtime.h>
#include <hip/hip_bf16.h>

typedef __bf16 bf16;
typedef __bf16 bf16x2 __attribute__((ext_vector_type(2)));
typedef __bf16 bf16x4 __attribute__((ext_vector_type(4)));
typedef __bf16 bf16x8 __attribute__((ext_vector_type(8)));
typedef float  f32x4  __attribute__((ext_vector_type(4)));
typedef int    i32x2  __attribute__((ext_vector_type(2)));
typedef int    i32x4  __attribute__((ext_vector_type(4)));

#define NEG_INF (-1e9f)
#define N_SCENES 2048

#if defined(__has_builtin)
#if __has_builtin(__builtin_amdgcn_exp2f)
#define EXP2(x) __builtin_amdgcn_exp2f(x)
#endif
#endif
#ifndef EXP2
#define EXP2(x) exp2f(x)
#endif

// v_permlane32_swap_b32: a' = {a.lo32lanes, b.lo32lanes}, b' = {a.hi, b.hi}
static __device__ __forceinline__ void pl32(int& a, int& b) {
#if defined(__has_builtin) && __has_builtin(__builtin_amdgcn_permlane32_swap)
    i32x2 res = __builtin_amdgcn_permlane32_swap(a, b, false, false);
    a = res[0]; b = res[1];
#else
    asm("v_permlane32_swap_b32 %0, %1" : "+v"(a), "+v"(b));
#endif
}

// pack two f32 -> one dword of 2 bf16 (compiler emits v_cvt_pk_bf16_f32)
static __device__ __forceinline__ int pk2(float x, float y) {
    bf16x2 t = {(bf16)x, (bf16)y};
    return __builtin_bit_cast(int, t);
}

// Quad-transpose transform (no LDS, no bpermute):
// sources a0,a1 (tile A words), b0,b1 (tile B words), each word = 2 bf16.
// Source layout: lane(r,qd') word w of tile T = elems [T*16 + qd'*4 + 2w, +1].
// Target: word j at lane(r,qd) = elems [qd*8 + 2j, +1] (A for qd<2, B else).
static __device__ __forceinline__ i32x4 qtrans(int a0, int a1, int b0, int b1,
                                               bool qodd) {
    i32x4 out;
    pl32(a0, b0);                       // a0={A.lo,B.lo}  b0={A.hi,B.hi}
    int y2 = __shfl_xor(b0, 16);
    int x2 = __shfl_xor(a0, 16);
    out[0] = qodd ? y2 : a0;
    out[2] = qodd ? b0 : x2;
    pl32(a1, b1);
    int y2b = __shfl_xor(b1, 16);
    int x2b = __shfl_xor(a1, 16);
    out[1] = qodd ? y2b : a1;
    out[3] = qodd ? b1 : x2b;
    return out;
}

// ---------------------------------------------------------------------------
// Prep: block 0: exclusive prefix sum of agents (B=2048); blocks 1..64:
// fp32 -> bf16 weight conversion into workspace.
// ---------------------------------------------------------------------------
__global__ __launch_bounds__(256) void prep_kernel(
    const float* __restrict__ w_in, const float* __restrict__ w_out,
    const int* __restrict__ agents,
    bf16* __restrict__ w_in_b, bf16* __restrict__ w_out_b, int* __restrict__ offs)
{
    __shared__ int tot[256];
    const int t = threadIdx.x;
    if (blockIdx.x == 0) {
        int loc[8]; int s = 0;
        #pragma unroll
        for (int j = 0; j < 8; ++j) { loc[j] = agents[t * 8 + j]; s += loc[j]; }
        tot[t] = s;
        __syncthreads();
        for (int o = 1; o < 256; o <<= 1) {
            int v = (t >= o) ? tot[t - o] : 0;
            __syncthreads();
            tot[t] += v;
            __syncthreads();
        }
        int run = tot[t] - s;
        #pragma unroll
        for (int j = 0; j < 8; ++j) { offs[t * 8 + j] = run; run += loc[j]; }
    } else {
        int i = (blockIdx.x - 1) * 1024 + t * 4;
        float4 v; bf16* dst;
        if (i < 49152) { v = *(const float4*)(w_in + i);            dst = w_in_b + i; }
        else           { v = *(const float4*)(w_out + (i - 49152)); dst = w_out_b + (i - 49152); }
        bf16x4 o = { (bf16)v.x, (bf16)v.y, (bf16)v.z, (bf16)v.w };
        *(bf16x4*)dst = o;
    }
}

// ---------------------------------------------------------------------------
// R14: consolidation to the session-best structure. R7 body VERBATIM
// (grid 2048, one scene/block, 4 waves, (256,4), K/V via 32KB LDS, Q in
// regs, qtrans quad-transposes, ctxS overlays Kld) + the single delta
// proven safe in three passing runs (R11/R12/R13): (1/sqrt32)*log2e folded
// into the Q pack, deleting the per-mt S-scale VALU pass.
// Lessons encoded: (a) any structure needing >128 total regs at (256,4)
// spills (R5/R8/R9/R10); (b) persistent loops trigger allocator demotion
// to scratch regardless of fence placement (R12: hoist-spill, R13:
// demotion-spill at unchanged VGPR count -- check FETCH/WRITE vs floor
// 18.6/67.7MB to detect); (c) 8-wave split duplicates per-head loads and
// loses (R5/R6); (d) occupancy knobs (LDS 16KB, cap 3/4/5) do not move
// the ~76us floor -- it is per-wave chain latency.
// MFMA 16x16x32_bf16: A[m=lane&15][k=quad*8+jj], B[k=quad*8+jj][n=lane&15],
// C/D: col=lane&15, row=quad*4+reg.
// ---------------------------------------------------------------------------
__global__ __launch_bounds__(256, 4) void attn_kernel(
    const float* __restrict__ att_in,
    const float* __restrict__ b_in, const float* __restrict__ b_out,
    const bf16* __restrict__ w_in_b, const bf16* __restrict__ w_out_b,
    const int* __restrict__ agents, const int* __restrict__ offs,
    float* __restrict__ out)
{
    __shared__ bf16 s_lds[4 * 4096];   // 32 KB

    const int b    = blockIdx.x;
    const int tid  = threadIdx.x;
    const int lane = tid & 63;
    const int w    = tid >> 6;         // wave id == head id
    const int h    = w;
    const int r    = lane & 15;
    const int qd   = lane >> 4;        // quad 0..3
    const int q1   = qd & 1;
    const int qh   = qd >> 1;
    const bool qodd = (q1 != 0);
    const int nb   = agents[b];
    const int off  = offs[b];
    const int mtc  = (nb + 15) >> 4;   // live m-tiles (1..4)

    bf16* Kld = s_lds + h * 4096;      // K[64][32] swizzled; later ctxS[4mt][64][8]
    bf16* vT  = Kld + 2048;            // vT[32][64]

    // ---- zero-fill output rows [nb, 64) ----
    {
        const float4 z4 = make_float4(0.f, 0.f, 0.f, 0.f);
        const int nz = (64 - nb) * 32;
        for (int i = tid; i < nz; i += 256) {
            int row = nb + (i >> 5);
            *(float4*)(out + ((size_t)b * 64 + row) * 128 + (i & 31) * 4) = z4;
        }
    }

    // ---- zero vT units for agents >= mtc*16 (keep PV inputs finite) ----
    {
        bf16x4 z4 = {(bf16)0.f,(bf16)0.f,(bf16)0.f,(bf16)0.f};
        int zrow = lane >> 1, zh = lane & 1;     // 32 rows x 2 halves
        #pragma unroll
        for (int un = 2; un < 8; ++un)
            if (un >= 2 * mtc) {
                int uu = un ^ (zrow & 7);
                *(bf16x4*)(vT + zrow * 64 + uu * 8 + zh * 4) = z4;
            }
    }

    // ---- x fragments from global (rows >= nb -> 0); serve as A and B ----
    bf16x8 xa[4][4];
    #pragma unroll
    for (int mt = 0; mt < 4; ++mt) {
        const int xrow = mt * 16 + r;
        const bool vr = xrow < nb;
        const float* px = att_in + (((size_t)(off + xrow)) << 7) + qd * 8;
        #pragma unroll
        for (int ks = 0; ks < 4; ++ks) {
            float4 lo = make_float4(0.f,0.f,0.f,0.f), hi = lo;
            if (vr) {
                lo = *(const float4*)(px + ks * 32);
                hi = *(const float4*)(px + ks * 32 + 4);
            }
            i32x4 pw4 = { pk2(lo.x, lo.y), pk2(lo.z, lo.w),
                          pk2(hi.x, hi.y), pk2(hi.z, hi.w) };
            xa[mt][ks] = __builtin_bit_cast(bf16x8, pw4);
        }
    }

    const float SC = 0.25503484f;      // (1/sqrt(32)) * log2(e), folded into Q

    // ---- stage 1a: Q tiles -> registers (packed, bias+scale folded) ----
    // qreg[mt][jt] @ lane(r,qd) = SC*(Q[agent=mt*16+r][d=jt*16+qd*4+reg]+bias)
    bf16x4 qreg[4][2];
    #pragma unroll
    for (int jt = 0; jt < 2; ++jt) {
        const int j0 = h * 32 + jt * 16;
        const bf16* pw = w_in_b + (size_t)(j0 + r) * 128 + qd * 8;
        bf16x8 wb[4];
        #pragma unroll
        for (int ks = 0; ks < 4; ++ks)
            wb[ks] = *(const bf16x8*)(pw + ks * 32);
        const float4 b4 = *(const float4*)(b_in + j0 + qd * 4);
        #pragma unroll
        for (int mt = 0; mt < 4; ++mt)
            if (mt < mtc) {
                f32x4 acc = {0.f,0.f,0.f,0.f};
                #pragma unroll
                for (int ks = 0; ks < 4; ++ks)
                    acc = __builtin_amdgcn_mfma_f32_16x16x32_bf16(wb[ks], xa[mt][ks], acc, 0, 0, 0);
                qreg[mt][jt] = (bf16x4){(bf16)((acc[0]+b4.x)*SC), (bf16)((acc[1]+b4.y)*SC),
                                        (bf16)((acc[2]+b4.z)*SC), (bf16)((acc[3]+b4.w)*SC)};
            }
    }

    // ---- stage 1b: K tiles -> LDS (swizzled) ----
    #pragma unroll
    for (int jt = 0; jt < 2; ++jt) {
        const int j0 = 128 + h * 32 + jt * 16;
        const bf16* pw = w_in_b + (size_t)(j0 + r) * 128 + qd * 8;
        bf16x8 wb[4];
        #pragma unroll
        for (int ks = 0; ks < 4; ++ks)
            wb[ks] = *(const bf16x8*)(pw + ks * 32);
        const float4 b4 = *(const float4*)(b_in + j0 + qd * 4);
        #pragma unroll
        for (int mt = 0; mt < 4; ++mt)
            if (mt < mtc) {
                f32x4 acc = {0.f,0.f,0.f,0.f};
                #pragma unroll
                for (int ks = 0; ks < 4; ++ks)
                    acc = __builtin_amdgcn_mfma_f32_16x16x32_bf16(wb[ks], xa[mt][ks], acc, 0, 0, 0);
                bf16x4 pk = {(bf16)(acc[0]+b4.x), (bf16)(acc[1]+b4.y),
                             (bf16)(acc[2]+b4.z), (bf16)(acc[3]+b4.w)};
                int rowa = mt * 16 + r;
                int uu = (jt * 2 + qh) ^ (rowa & 3);
                *(bf16x4*)(Kld + rowa * 32 + uu * 8 + q1 * 4) = pk;
            }
    }

    // ---- stage 1c: V tiles -> LDS transposed ----
    #pragma unroll
    for (int jt = 0; jt < 2; ++jt) {
        const int j0 = 256 + h * 32 + jt * 16;
        const bf16* pw = w_in_b + (size_t)(j0 + r) * 128 + qd * 8;
        bf16x8 wb[4];
        #pragma unroll
        for (int ks = 0; ks < 4; ++ks)
            wb[ks] = *(const bf16x8*)(pw + ks * 32);
        const float bv = b_in[j0 + r];
        #pragma unroll
        for (int mt = 0; mt < 4; ++mt)
            if (mt < mtc) {
                f32x4 acc = {0.f,0.f,0.f,0.f};
                #pragma unroll
                for (int ks = 0; ks < 4; ++ks)
                    acc = __builtin_amdgcn_mfma_f32_16x16x32_bf16(xa[mt][ks], wb[ks], acc, 0, 0, 0);
                bf16x4 pk = {(bf16)(acc[0]+bv), (bf16)(acc[1]+bv),
                             (bf16)(acc[2]+bv), (bf16)(acc[3]+bv)};
                int rowd = jt * 16 + r;
                int uu = (mt * 2 + qh) ^ (rowd & 7);
                *(bf16x4*)(vT + rowd * 64 + uu * 8 + q1 * 4) = pk;
            }
    }

    // ---- stage 2 preloads: K A-frags, V^T A-frags (wave-local LDS) ----
    bf16x8 kf[4];
    #pragma unroll
    for (int nt = 0; nt < 4; ++nt)
        if (nt < mtc) {
            int row = nt * 16 + r;
            kf[nt] = *(const bf16x8*)(Kld + row * 32 + (qd ^ (row & 3)) * 8);
        }
    bf16x8 vf[2][2];
    #pragma unroll
    for (int dt = 0; dt < 2; ++dt)
        #pragma unroll
        for (int hk = 0; hk < 2; ++hk) {
            int row = dt * 16 + r;
            vf[dt][hk] = *(const bf16x8*)(vT + row * 64 + ((hk * 4 + qd) ^ (row & 7)) * 8);
        }
    bf16x8 wof[2][4]; float4 bo4[2];
    #pragma unroll
    for (int t2 = 0; t2 < 2; ++t2) {
        const int jg = (h * 2 + t2) * 16;
        const bf16* pw = w_out_b + (size_t)(jg + r) * 128 + qd * 8;
        #pragma unroll
        for (int s = 0; s < 4; ++s)
            wof[t2][s] = *(const bf16x8*)(pw + s * 32);
        bo4[t2] = *(const float4*)(b_out + jg + qd * 4);
    }

    // ---- stage 2: per query-tile mt: S^T -> softmax -> P^T -> PV ----
    #pragma unroll
    for (int mt = 0; mt < 4; ++mt)
        if (mt < mtc) {
            // qf = B-frag Q[agent=r][d=qd*8+jj] from qreg via quad-transform
            i32x2 qa = __builtin_bit_cast(i32x2, qreg[mt][0]);
            i32x2 qb = __builtin_bit_cast(i32x2, qreg[mt][1]);
            i32x4 qw = qtrans(qa[0], qa[1], qb[0], qb[1], qodd);
            bf16x8 qf = __builtin_bit_cast(bf16x8, qw);

            f32x4 S[4];
            #pragma unroll
            for (int nt = 0; nt < 4; ++nt)
                if (nt < mtc) {
                    f32x4 z = {0.f,0.f,0.f,0.f};
                    S[nt] = __builtin_amdgcn_mfma_f32_16x16x32_bf16(kf[nt], qf, z, 0, 0, 0);
                }
            // masked softmax (log2 domain; scale pre-folded into Q)
            #pragma unroll
            for (int nt = 0; nt < 4; ++nt) {
                if (nt < mtc) {
                    #pragma unroll
                    for (int i = 0; i < 4; ++i) {
                        bool kv = (nt * 16 + qd * 4 + i) < nb;
                        S[nt][i] = kv ? S[nt][i] : NEG_INF;
                    }
                } else {
                    S[nt] = (f32x4){NEG_INF, NEG_INF, NEG_INF, NEG_INF};
                }
            }
            float tm[4];
            #pragma unroll
            for (int nt = 0; nt < 4; ++nt)
                tm[nt] = fmaxf(fmaxf(S[nt][0], S[nt][1]), fmaxf(S[nt][2], S[nt][3]));
            float mx = fmaxf(fmaxf(tm[0], tm[1]), fmaxf(tm[2], tm[3]));
            mx = fmaxf(mx, __shfl_xor(mx, 16));
            mx = fmaxf(mx, __shfl_xor(mx, 32));
            float lt[4];
            #pragma unroll
            for (int nt = 0; nt < 4; ++nt) {
                float e0 = EXP2(S[nt][0] - mx), e1 = EXP2(S[nt][1] - mx);
                float e2 = EXP2(S[nt][2] - mx), e3 = EXP2(S[nt][3] - mx);
                S[nt][0] = e0; S[nt][1] = e1; S[nt][2] = e2; S[nt][3] = e3;
                lt[nt] = (e0 + e1) + (e2 + e3);
            }
            float l = (lt[0] + lt[1]) + (lt[2] + lt[3]);
            l += __shfl_xor(l, 16);
            l += __shfl_xor(l, 32);
            const float rl = 1.0f / l;
            #pragma unroll
            for (int nt = 0; nt < 4; ++nt)
                #pragma unroll
                for (int i = 0; i < 4; ++i)
                    S[nt][i] *= rl;                       // invalid keys -> exact 0

            // PV: O^T = V^T * P^T ; P^T frags via quad-transform
            f32x4 o0 = {0.f,0.f,0.f,0.f}, o1 = {0.f,0.f,0.f,0.f};
            #pragma unroll
            for (int hk = 0; hk < 2; ++hk)
                if (hk * 2 < mtc) {
                    int a0 = pk2(S[2*hk  ][0], S[2*hk  ][1]);
                    int a1 = pk2(S[2*hk  ][2], S[2*hk  ][3]);
                    int b0 = pk2(S[2*hk+1][0], S[2*hk+1][1]);
                    int b1 = pk2(S[2*hk+1][2], S[2*hk+1][3]);
                    i32x4 pw4 = qtrans(a0, a1, b0, b1, qodd);
                    bf16x8 pf = __builtin_bit_cast(bf16x8, pw4);
                    o0 = __builtin_amdgcn_mfma_f32_16x16x32_bf16(vf[0][hk], pf, o0, 0, 0, 0);
                    o1 = __builtin_amdgcn_mfma_f32_16x16x32_bf16(vf[1][hk], pf, o1, 0, 0, 0);
                }

            // ctx^T B-frag via quad-transform -> one b128 LDS write (ctxS
            // overlays Kld; kf register-resident; wave-local region)
            {
                int a0 = pk2(o0[0], o0[1]);
                int a1 = pk2(o0[2], o0[3]);
                int b0 = pk2(o1[0], o1[1]);
                int b1 = pk2(o1[2], o1[3]);
                i32x4 cw = qtrans(a0, a1, b0, b1, qodd);
                bf16x8 cf = __builtin_bit_cast(bf16x8, cw);
                *(bf16x8*)(Kld + mt * 512 + lane * 8) = cf;   // ctxS[h][mt][lane]
            }
        }
    __syncthreads();

    // ---- stage 3: out^T = W_out * ctx^T ; float4 stores ----
    #pragma unroll
    for (int mt = 0; mt < 4; ++mt)
        if (mt < mtc) {
            bf16x8 cb[4];
            #pragma unroll
            for (int s = 0; s < 4; ++s)
                cb[s] = *(const bf16x8*)(s_lds + s * 4096 + mt * 512 + lane * 8);
            const int rowa = mt * 16 + r;
            #pragma unroll
            for (int t2 = 0; t2 < 2; ++t2) {
                f32x4 acc = {0.f,0.f,0.f,0.f};
                #pragma unroll
                for (int s = 0; s < 4; ++s)
                    acc = __builtin_amdgcn_mfma_f32_16x16x32_bf16(wof[t2][s], cb[s], acc, 0, 0, 0);
                if (rowa < nb) {
                    float4 o4 = make_float4(acc[0] + bo4[t2].x, acc[1] + bo4[t2].y,
                                            acc[2] + bo4[t2].z, acc[3] + bo4[t2].w);
                    *(float4*)(out + ((size_t)b * 64 + rowa) * 128
                               + (w * 2 + t2) * 16 + qd * 4) = o4;
                }
            }
        }
}

extern "C" void kernel_launch(void* const* d_in, const int* in_sizes, int n_in,
                              void* d_out, int out_size, void* d_ws, size_t ws_size,
                              hipStream_t stream)
{
    const float* att_in = (const float*)d_in[0];
    const float* w_in   = (const float*)d_in[1];
    const float* b_in   = (const float*)d_in[2];
    const float* w_out  = (const float*)d_in[3];
    const float* b_out  = (const float*)d_in[4];
    const int*   agents = (const int*)d_in[5];

    bf16* w_in_b  = (bf16*)d_ws;                         // 49152 * 2B
    bf16* w_out_b = w_in_b + 49152;                      // 16384 * 2B
    int*  offs    = (int*)((char*)d_ws + 98304 + 32768); // 2048 * 4B

    prep_kernel<<<65, 256, 0, stream>>>(w_in, w_out, agents, w_in_b, w_out_b, offs);
    attn_kernel<<<N_SCENES, 256, 0, stream>>>(att_in, b_in, b_out, w_in_b, w_out_b,
                                              agents, offs, (float*)d_out);
}

// Round 11
// 170.077 us; speedup vs baseline: 2.7761x; 1.1435x over previous
//
#include <hip/hip_runtime.h>
#include <hip/hip_bf16.h>

typedef __bf16 bf16;
typedef __bf16 bf16x2 __attribute__((ext_vector_type(2)));
typedef __bf16 bf16x4 __attribute__((ext_vector_type(4)));
typedef __bf16 bf16x8 __attribute__((ext_vector_type(8)));
typedef float  f32x4  __attribute__((ext_vector_type(4)));
typedef int    i32x2  __attribute__((ext_vector_type(2)));
typedef int    i32x4  __attribute__((ext_vector_type(4)));

#define NEG_INF (-1e9f)
#define N_SCENES 2048

#if defined(__has_builtin)
#if __has_builtin(__builtin_amdgcn_exp2f)
#define EXP2(x) __builtin_amdgcn_exp2f(x)
#endif
#endif
#ifndef EXP2
#define EXP2(x) exp2f(x)
#endif

// v_permlane32_swap_b32: a' = {a.lo32lanes, b.lo32lanes}, b' = {a.hi, b.hi}
static __device__ __forceinline__ void pl32(int& a, int& b) {
#if defined(__has_builtin) && __has_builtin(__builtin_amdgcn_permlane32_swap)
    i32x2 res = __builtin_amdgcn_permlane32_swap(a, b, false, false);
    a = res[0]; b = res[1];
#else
    asm("v_permlane32_swap_b32 %0, %1" : "+v"(a), "+v"(b));
#endif
}

// pack two f32 -> one dword of 2 bf16 (compiler emits v_cvt_pk_bf16_f32)
static __device__ __forceinline__ int pk2(float x, float y) {
    bf16x2 t = {(bf16)x, (bf16)y};
    return __builtin_bit_cast(int, t);
}

// Quad-transpose transform (replaces the 16-bpermute quad-shuffle):
// sources a0,a1 (tile A words), b0,b1 (tile B words), each word = 2 bf16.
// Source layout: lane(r,qd') word w of tile T = elems [T*16 + qd'*4 + 2w, +1].
// Target: word j at lane(r,qd) = elems [qd*8 + 2j, +1] (A for qd<2, B else).
static __device__ __forceinline__ i32x4 qtrans(int a0, int a1, int b0, int b1,
                                               bool qodd) {
    i32x4 out;
    pl32(a0, b0);                       // a0={A.lo,B.lo}  b0={A.hi,B.hi}
    int y2 = __shfl_xor(b0, 16);
    int x2 = __shfl_xor(a0, 16);
    out[0] = qodd ? y2 : a0;
    out[2] = qodd ? b0 : x2;
    pl32(a1, b1);
    int y2b = __shfl_xor(b1, 16);
    int x2b = __shfl_xor(a1, 16);
    out[1] = qodd ? y2b : a1;
    out[3] = qodd ? b1 : x2b;
    return out;
}

// ---------------------------------------------------------------------------
// Prep: block 0: exclusive prefix sum of agents (B=2048); blocks 1..64:
// fp32 -> bf16 weight conversion into workspace.
// ---------------------------------------------------------------------------
__global__ __launch_bounds__(256) void prep_kernel(
    const float* __restrict__ w_in, const float* __restrict__ w_out,
    const int* __restrict__ agents,
    bf16* __restrict__ w_in_b, bf16* __restrict__ w_out_b, int* __restrict__ offs)
{
    __shared__ int tot[256];
    const int t = threadIdx.x;
    if (blockIdx.x == 0) {
        int loc[8]; int s = 0;
        #pragma unroll
        for (int j = 0; j < 8; ++j) { loc[j] = agents[t * 8 + j]; s += loc[j]; }
        tot[t] = s;
        __syncthreads();
        for (int o = 1; o < 256; o <<= 1) {
            int v = (t >= o) ? tot[t - o] : 0;
            __syncthreads();
            tot[t] += v;
            __syncthreads();
        }
        int run = tot[t] - s;
        #pragma unroll
        for (int j = 0; j < 8; ++j) { offs[t * 8 + j] = run; run += loc[j]; }
    } else {
        int i = (blockIdx.x - 1) * 1024 + t * 4;
        float4 v; bf16* dst;
        if (i < 49152) { v = *(const float4*)(w_in + i);            dst = w_in_b + i; }
        else           { v = *(const float4*)(w_out + (i - 49152)); dst = w_out_b + (i - 49152); }
        bf16x4 o = { (bf16)v.x, (bf16)v.y, (bf16)v.z, (bf16)v.w };
        *(bf16x4*)dst = o;
    }
}

// ---------------------------------------------------------------------------
// R15: BYTE-FOR-BYTE reproduction of R7, the session-best verified artifact
// (attn 76us, total 171.1us; clean: VGPR 64, SGPR 112, FETCH 18.6MB,
// WRITE 67.7MB). R14 ("R7 + safe deltas") spilled (+26/+62MB at identical
// reported VGPR/SGPR) -- its two real deltas vs R7 were the SC*log2e fold
// in the qreg pack and the pk2/i32x4 xa pack (inherited from the R8
// lineage; true R7 uses direct (bf16) element casts in xa). One or both
// trigger allocator demotion-to-scratch. This submission restores R7
// exactly: 4 waves, wave=head, Q in regs, K/V via 32KB LDS (swizzled),
// qtrans quad-transposes for qf/P^T/ctx^T, ctxS overlays Kld, log2-domain
// softmax with k1 = (1/sqrt32)*log2e applied in stage 2.
// Spill detector for future edits: FETCH > 20MB or WRITE > 70MB = scratch.
// MFMA 16x16x32_bf16: A[m=lane&15][k=quad*8+jj], B[k=quad*8+jj][n=lane&15],
// C/D: col=lane&15, row=quad*4+reg.
// ---------------------------------------------------------------------------
__global__ __launch_bounds__(256, 4) void attn_kernel(
    const float* __restrict__ att_in,
    const float* __restrict__ b_in, const float* __restrict__ b_out,
    const bf16* __restrict__ w_in_b, const bf16* __restrict__ w_out_b,
    const int* __restrict__ agents, const int* __restrict__ offs,
    float* __restrict__ out)
{
    __shared__ bf16 s_lds[4 * 4096];   // 32 KB

    const int b    = blockIdx.x;
    const int tid  = threadIdx.x;
    const int lane = tid & 63;
    const int w    = tid >> 6;         // wave id == head id
    const int h    = w;
    const int r    = lane & 15;
    const int qd   = lane >> 4;        // quad 0..3
    const int q1   = qd & 1;
    const int qh   = qd >> 1;
    const bool qodd = (q1 != 0);
    const int nb   = agents[b];
    const int off  = offs[b];
    const int mtc  = (nb + 15) >> 4;   // live m-tiles (1..4)

    bf16* Kld = s_lds + h * 4096;      // K[64][32] swizzled; later ctxS[4mt][64][8]
    bf16* vT  = Kld + 2048;            // vT[32][64]

    // ---- zero-fill output rows [nb, 64) ----
    {
        const float4 z4 = make_float4(0.f, 0.f, 0.f, 0.f);
        const int nz = (64 - nb) * 32;
        for (int i = tid; i < nz; i += 256) {
            int row = nb + (i >> 5);
            *(float4*)(out + ((size_t)b * 64 + row) * 128 + (i & 31) * 4) = z4;
        }
    }

    // ---- zero vT units for agents >= mtc*16 (keep PV inputs finite) ----
    {
        bf16x4 z4 = {(bf16)0.f,(bf16)0.f,(bf16)0.f,(bf16)0.f};
        int zrow = lane >> 1, zh = lane & 1;     // 32 rows x 2 halves
        #pragma unroll
        for (int un = 2; un < 8; ++un)
            if (un >= 2 * mtc) {
                int uu = un ^ (zrow & 7);
                *(bf16x4*)(vT + zrow * 64 + uu * 8 + zh * 4) = z4;
            }
    }

    // ---- x fragments from global (rows >= nb -> 0); serve as A and B ----
    bf16x8 xa[4][4];
    #pragma unroll
    for (int mt = 0; mt < 4; ++mt) {
        const int xrow = mt * 16 + r;
        const bool vr = xrow < nb;
        const float* px = att_in + (((size_t)(off + xrow)) << 7) + qd * 8;
        #pragma unroll
        for (int ks = 0; ks < 4; ++ks) {
            float4 lo = make_float4(0.f,0.f,0.f,0.f), hi = lo;
            if (vr) {
                lo = *(const float4*)(px + ks * 32);
                hi = *(const float4*)(px + ks * 32 + 4);
            }
            xa[mt][ks] = (bf16x8){(bf16)lo.x,(bf16)lo.y,(bf16)lo.z,(bf16)lo.w,
                                  (bf16)hi.x,(bf16)hi.y,(bf16)hi.z,(bf16)hi.w};
        }
    }

    // ---- stage 1a: Q tiles -> registers (packed with bias) ----
    // qreg[mt][jt] at lane(r,qd) = Q[agent=mt*16+r][d = jt*16+qd*4+reg]+bias
    bf16x4 qreg[4][2];
    #pragma unroll
    for (int jt = 0; jt < 2; ++jt) {
        const int j0 = h * 32 + jt * 16;
        const bf16* pw = w_in_b + (size_t)(j0 + r) * 128 + qd * 8;
        bf16x8 wb[4];
        #pragma unroll
        for (int ks = 0; ks < 4; ++ks)
            wb[ks] = *(const bf16x8*)(pw + ks * 32);
        const float4 b4 = *(const float4*)(b_in + j0 + qd * 4);
        #pragma unroll
        for (int mt = 0; mt < 4; ++mt)
            if (mt < mtc) {
                f32x4 acc = {0.f,0.f,0.f,0.f};
                #pragma unroll
                for (int ks = 0; ks < 4; ++ks)
                    acc = __builtin_amdgcn_mfma_f32_16x16x32_bf16(wb[ks], xa[mt][ks], acc, 0, 0, 0);
                qreg[mt][jt] = (bf16x4){(bf16)(acc[0]+b4.x), (bf16)(acc[1]+b4.y),
                                        (bf16)(acc[2]+b4.z), (bf16)(acc[3]+b4.w)};
            }
    }

    // ---- stage 1b: K tiles -> LDS (swizzled, as R4) ----
    #pragma unroll
    for (int jt = 0; jt < 2; ++jt) {
        const int j0 = 128 + h * 32 + jt * 16;
        const bf16* pw = w_in_b + (size_t)(j0 + r) * 128 + qd * 8;
        bf16x8 wb[4];
        #pragma unroll
        for (int ks = 0; ks < 4; ++ks)
            wb[ks] = *(const bf16x8*)(pw + ks * 32);
        const float4 b4 = *(const float4*)(b_in + j0 + qd * 4);
        #pragma unroll
        for (int mt = 0; mt < 4; ++mt)
            if (mt < mtc) {
                f32x4 acc = {0.f,0.f,0.f,0.f};
                #pragma unroll
                for (int ks = 0; ks < 4; ++ks)
                    acc = __builtin_amdgcn_mfma_f32_16x16x32_bf16(wb[ks], xa[mt][ks], acc, 0, 0, 0);
                bf16x4 pk = {(bf16)(acc[0]+b4.x), (bf16)(acc[1]+b4.y),
                             (bf16)(acc[2]+b4.z), (bf16)(acc[3]+b4.w)};
                int rowa = mt * 16 + r;
                int uu = (jt * 2 + qh) ^ (rowa & 3);
                *(bf16x4*)(Kld + rowa * 32 + uu * 8 + q1 * 4) = pk;
            }
    }

    // ---- stage 1c: V tiles -> LDS transposed (as R4) ----
    #pragma unroll
    for (int jt = 0; jt < 2; ++jt) {
        const int j0 = 256 + h * 32 + jt * 16;
        const bf16* pw = w_in_b + (size_t)(j0 + r) * 128 + qd * 8;
        bf16x8 wb[4];
        #pragma unroll
        for (int ks = 0; ks < 4; ++ks)
            wb[ks] = *(const bf16x8*)(pw + ks * 32);
        const float bv = b_in[j0 + r];
        #pragma unroll
        for (int mt = 0; mt < 4; ++mt)
            if (mt < mtc) {
                f32x4 acc = {0.f,0.f,0.f,0.f};
                #pragma unroll
                for (int ks = 0; ks < 4; ++ks)
                    acc = __builtin_amdgcn_mfma_f32_16x16x32_bf16(xa[mt][ks], wb[ks], acc, 0, 0, 0);
                bf16x4 pk = {(bf16)(acc[0]+bv), (bf16)(acc[1]+bv),
                             (bf16)(acc[2]+bv), (bf16)(acc[3]+bv)};
                int rowd = jt * 16 + r;
                int uu = (mt * 2 + qh) ^ (rowd & 7);
                *(bf16x4*)(vT + rowd * 64 + uu * 8 + q1 * 4) = pk;
            }
    }

    // ---- stage 2 preloads: K A-frags, V^T A-frags (wave-local LDS) ----
    bf16x8 kf[4];
    #pragma unroll
    for (int nt = 0; nt < 4; ++nt)
        if (nt < mtc) {
            int row = nt * 16 + r;
            kf[nt] = *(const bf16x8*)(Kld + row * 32 + (qd ^ (row & 3)) * 8);
        }
    bf16x8 vf[2][2];
    #pragma unroll
    for (int dt = 0; dt < 2; ++dt)
        #pragma unroll
        for (int hk = 0; hk < 2; ++hk) {
            int row = dt * 16 + r;
            vf[dt][hk] = *(const bf16x8*)(vT + row * 64 + ((hk * 4 + qd) ^ (row & 7)) * 8);
        }
    bf16x8 wof[2][4]; float4 bo4[2];
    #pragma unroll
    for (int t2 = 0; t2 < 2; ++t2) {
        const int jg = (h * 2 + t2) * 16;
        const bf16* pw = w_out_b + (size_t)(jg + r) * 128 + qd * 8;
        #pragma unroll
        for (int s = 0; s < 4; ++s)
            wof[t2][s] = *(const bf16x8*)(pw + s * 32);
        bo4[t2] = *(const float4*)(b_out + jg + qd * 4);
    }

    const float k1 = 0.25503484f;      // (1/sqrt(32)) * log2(e)

    // ---- stage 2: per query-tile mt: S^T -> softmax -> P^T -> PV ----
    #pragma unroll
    for (int mt = 0; mt < 4; ++mt)
        if (mt < mtc) {
            // qf = B-frag Q[agent=r][d=qd*8+jj] from qreg via quad-transform
            i32x2 qa = __builtin_bit_cast(i32x2, qreg[mt][0]);
            i32x2 qb = __builtin_bit_cast(i32x2, qreg[mt][1]);
            i32x4 qw = qtrans(qa[0], qa[1], qb[0], qb[1], qodd);
            bf16x8 qf = __builtin_bit_cast(bf16x8, qw);

            f32x4 S[4];
            #pragma unroll
            for (int nt = 0; nt < 4; ++nt)
                if (nt < mtc) {
                    f32x4 z = {0.f,0.f,0.f,0.f};
                    S[nt] = __builtin_amdgcn_mfma_f32_16x16x32_bf16(kf[nt], qf, z, 0, 0, 0);
                }
            // masked softmax (log2 domain) over keys n = nt*16 + qd*4 + i
            #pragma unroll
            for (int nt = 0; nt < 4; ++nt) {
                if (nt < mtc) {
                    #pragma unroll
                    for (int i = 0; i < 4; ++i) {
                        bool kv = (nt * 16 + qd * 4 + i) < nb;
                        S[nt][i] = kv ? S[nt][i] * k1 : NEG_INF;
                    }
                } else {
                    S[nt] = (f32x4){NEG_INF, NEG_INF, NEG_INF, NEG_INF};
                }
            }
            float tm[4];
            #pragma unroll
            for (int nt = 0; nt < 4; ++nt)
                tm[nt] = fmaxf(fmaxf(S[nt][0], S[nt][1]), fmaxf(S[nt][2], S[nt][3]));
            float mx = fmaxf(fmaxf(tm[0], tm[1]), fmaxf(tm[2], tm[3]));
            mx = fmaxf(mx, __shfl_xor(mx, 16));
            mx = fmaxf(mx, __shfl_xor(mx, 32));
            float lt[4];
            #pragma unroll
            for (int nt = 0; nt < 4; ++nt) {
                float e0 = EXP2(S[nt][0] - mx), e1 = EXP2(S[nt][1] - mx);
                float e2 = EXP2(S[nt][2] - mx), e3 = EXP2(S[nt][3] - mx);
                S[nt][0] = e0; S[nt][1] = e1; S[nt][2] = e2; S[nt][3] = e3;
                lt[nt] = (e0 + e1) + (e2 + e3);
            }
            float l = (lt[0] + lt[1]) + (lt[2] + lt[3]);
            l += __shfl_xor(l, 16);
            l += __shfl_xor(l, 32);
            const float rl = 1.0f / l;
            #pragma unroll
            for (int nt = 0; nt < 4; ++nt)
                #pragma unroll
                for (int i = 0; i < 4; ++i)
                    S[nt][i] *= rl;                       // invalid keys -> exact 0

            // PV: O^T = V^T * P^T ; P^T frags via quad-transform (no bpermute)
            f32x4 o0 = {0.f,0.f,0.f,0.f}, o1 = {0.f,0.f,0.f,0.f};
            #pragma unroll
            for (int hk = 0; hk < 2; ++hk)
                if (hk * 2 < mtc) {
                    int a0 = pk2(S[2*hk  ][0], S[2*hk  ][1]);
                    int a1 = pk2(S[2*hk  ][2], S[2*hk  ][3]);
                    int b0 = pk2(S[2*hk+1][0], S[2*hk+1][1]);
                    int b1 = pk2(S[2*hk+1][2], S[2*hk+1][3]);
                    i32x4 pw4 = qtrans(a0, a1, b0, b1, qodd);
                    bf16x8 pf = __builtin_bit_cast(bf16x8, pw4);
                    o0 = __builtin_amdgcn_mfma_f32_16x16x32_bf16(vf[0][hk], pf, o0, 0, 0, 0);
                    o1 = __builtin_amdgcn_mfma_f32_16x16x32_bf16(vf[1][hk], pf, o1, 0, 0, 0);
                }

            // ctx^T B-frag via quad-transform -> one b128 LDS write (ctxS
            // overlays K; kf already register-resident; wave-local region)
            {
                int a0 = pk2(o0[0], o0[1]);
                int a1 = pk2(o0[2], o0[3]);
                int b0 = pk2(o1[0], o1[1]);
                int b1 = pk2(o1[2], o1[3]);
                i32x4 cw = qtrans(a0, a1, b0, b1, qodd);
                bf16x8 cf = __builtin_bit_cast(bf16x8, cw);
                *(bf16x8*)(Kld + mt * 512 + lane * 8) = cf;   // ctxS[h][mt][lane]
            }
        }
    __syncthreads();

    // ---- stage 3: out^T = W_out * ctx^T ; float4 stores ----
    #pragma unroll
    for (int mt = 0; mt < 4; ++mt)
        if (mt < mtc) {
            bf16x8 cb[4];
            #pragma unroll
            for (int s = 0; s < 4; ++s)
                cb[s] = *(const bf16x8*)(s_lds + s * 4096 + mt * 512 + lane * 8);
            const int rowa = mt * 16 + r;
            #pragma unroll
            for (int t2 = 0; t2 < 2; ++t2) {
                f32x4 acc = {0.f,0.f,0.f,0.f};
                #pragma unroll
                for (int s = 0; s < 4; ++s)
                    acc = __builtin_amdgcn_mfma_f32_16x16x32_bf16(wof[t2][s], cb[s], acc, 0, 0, 0);
                if (rowa < nb) {
                    float4 o4 = make_float4(acc[0] + bo4[t2].x, acc[1] + bo4[t2].y,
                                            acc[2] + bo4[t2].z, acc[3] + bo4[t2].w);
                    *(float4*)(out + ((size_t)b * 64 + rowa) * 128
                               + (w * 2 + t2) * 16 + qd * 4) = o4;
                }
            }
        }
}

extern "C" void kernel_launch(void* const* d_in, const int* in_sizes, int n_in,
                              void* d_out, int out_size, void* d_ws, size_t ws_size,
                              hipStream_t stream)
{
    const float* att_in = (const float*)d_in[0];
    const float* w_in   = (const float*)d_in[1];
    const float* b_in   = (const float*)d_in[2];
    const float* w_out  = (const float*)d_in[3];
    const float* b_out  = (const float*)d_in[4];
    const int*   agents = (const int*)d_in[5];

    bf16* w_in_b  = (bf16*)d_ws;                         // 49152 * 2B
    bf16* w_out_b = w_in_b + 49152;                      // 16384 * 2B
    int*  offs    = (int*)((char*)d_ws + 98304 + 32768); // 2048 * 4B

    prep_kernel<<<65, 256, 0, stream>>>(w_in, w_out, agents, w_in_b, w_out_b, offs);
    attn_kernel<<<N_SCENES, 256, 0, stream>>>(att_in, b_in, b_out, w_in_b, w_out_b,
                                              agents, offs, (float*)d_out);
}